// Round 3
// baseline (200.471 us; speedup 1.0000x reference)
//
#include <hip/hip_runtime.h>

// Problem constants (fixed by the reference)
#define M_ROWS 8
#define K_DIM  8192
#define N_DIM  28672

#define WAVES   4
#define BLOCK   256          // 4 waves
#define NPW     4            // n-rows per wave
#define NPB     (WAVES*NPW)  // 16 n-rows per block
#define KT      1024         // K-tile staged in LDS (32 KiB)

typedef __attribute__((ext_vector_type(4))) int   i32x4;
typedef __attribute__((ext_vector_type(4))) float f32x4;

__global__ __launch_bounds__(BLOCK) void w8a16_gemv_kernel(
    const float* __restrict__ x,      // [M,K] f32 (fp16 values upcast by harness)
    const int*   __restrict__ qw,     // [N,K] int32 (sign-extended int8)
    const float* __restrict__ scales, // [N]   f32
    const float* __restrict__ bias,   // [N]   f32
    float*       __restrict__ out)    // [M,N] f32
{
    __shared__ float xs[M_ROWS][KT];   // 32 KiB

    const int tid  = threadIdx.x;
    const int wave = tid >> 6;
    const int lane = tid & 63;
    const int n0   = blockIdx.x * NPB + wave * NPW;

    const int* qp[NPW];
#pragma unroll
    for (int j = 0; j < NPW; ++j)
        qp[j] = qw + (size_t)(n0 + j) * K_DIM;

    float acc[NPW][M_ROWS];
#pragma unroll
    for (int j = 0; j < NPW; ++j)
#pragma unroll
        for (int m = 0; m < M_ROWS; ++m) acc[j][m] = 0.0f;

    for (int kt = 0; kt < K_DIM; kt += KT) {
        __syncthreads();  // protect xs from readers of previous tile
        // Stage x[0:8, kt:kt+KT] into LDS. 8*1024 f32 = 2048 f32x4 chunks.
#pragma unroll
        for (int it = 0; it < (M_ROWS * KT / 4) / BLOCK; ++it) {
            int i  = (it * BLOCK + tid) * 4;      // element index within tile
            int m  = i / KT;
            int kk = i % KT;
            *reinterpret_cast<f32x4*>(&xs[m][kk]) =
                *reinterpret_cast<const f32x4*>(&x[(size_t)m * K_DIM + kt + kk]);
        }
        __syncthreads();

        // Inner: each lane covers 4 consecutive k per step; 64 lanes -> 256 k/step.
#pragma unroll
        for (int ki = 0; ki < KT; ki += 256) {
            const int kk = ki + (lane << 2);

            i32x4 q4[NPW];
#pragma unroll
            for (int j = 0; j < NPW; ++j)
                q4[j] = *reinterpret_cast<const i32x4*>(qp[j] + kt + kk);

            float qf[NPW][4];
#pragma unroll
            for (int j = 0; j < NPW; ++j) {
                qf[j][0] = (float)q4[j].x;
                qf[j][1] = (float)q4[j].y;
                qf[j][2] = (float)q4[j].z;
                qf[j][3] = (float)q4[j].w;
            }

#pragma unroll
            for (int m = 0; m < M_ROWS; ++m) {
                f32x4 xv = *reinterpret_cast<const f32x4*>(&xs[m][kk]);
#pragma unroll
                for (int j = 0; j < NPW; ++j) {
                    acc[j][m] += xv.x * qf[j][0];
                    acc[j][m] += xv.y * qf[j][1];
                    acc[j][m] += xv.z * qf[j][2];
                    acc[j][m] += xv.w * qf[j][3];
                }
            }
        }
    }

    // Cross-lane reduction (64 lanes) for each of the 32 accumulators.
#pragma unroll
    for (int j = 0; j < NPW; ++j) {
#pragma unroll
        for (int m = 0; m < M_ROWS; ++m) {
            float v = acc[j][m];
#pragma unroll
            for (int off = 32; off > 0; off >>= 1)
                v += __shfl_xor(v, off, 64);
            acc[j][m] = v;
        }
    }

    if (lane == 0) {
#pragma unroll
        for (int j = 0; j < NPW; ++j) {
            const int n = n0 + j;
            const float s = scales[n];
            const float b = bias[n];
#pragma unroll
            for (int m = 0; m < M_ROWS; ++m)
                out[(size_t)m * N_DIM + n] = s * acc[j][m] + b;
        }
    }
}

extern "C" void kernel_launch(void* const* d_in, const int* in_sizes, int n_in,
                              void* d_out, int out_size, void* d_ws, size_t ws_size,
                              hipStream_t stream) {
    const float* x      = (const float*)d_in[0];
    const int*   qw     = (const int*)d_in[1];
    const float* scales = (const float*)d_in[2];
    const float* bias   = (const float*)d_in[3];
    float*       out    = (float*)d_out;

    dim3 grid(N_DIM / NPB);   // 1792 blocks
    dim3 block(BLOCK);
    w8a16_gemv_kernel<<<grid, block, 0, stream>>>(x, qw, scales, bias, out);
}